// Round 7
// baseline (518.398 us; speedup 1.0000x reference)
//
#include <hip/hip_runtime.h>
#include <hip/hip_bf16.h>

#define NE   64
#define NH   1024
#define NF   2816
#define TPE  64
#define PITCH 72      // LDS pitch (validated in k2 at 7.1 TB/s)

typedef __attribute__((ext_vector_type(8))) short bf16x8;
typedef __attribute__((ext_vector_type(4))) float f32x4;

__device__ __forceinline__ ushort f2bf(float f) {
    union { float f; unsigned u; } v; v.f = f;
    unsigned r = v.u + 0x7fffu + ((v.u >> 16) & 1u);
    return (ushort)(r >> 16);
}

__device__ __forceinline__ bf16x8 cvt8(f32x4 lo, f32x4 hi) {
    bf16x8 r;
    #pragma unroll
    for (int j = 0; j < 4; ++j) {
        r[j]     = (short)f2bf(lo[j]);
        r[4 + j] = (short)f2bf(hi[j]);
    }
    return r;
}

// ---------------- Kernel 0: x (f32) -> xb (bf16), one pass -----------------
__global__ __launch_bounds__(256)
void xcast(const float* __restrict__ x, ushort* __restrict__ xb) {
    const int i = blockIdx.x * 256 + threadIdx.x;   // 8 elems per thread
    const f32x4 a = *(const f32x4*)(x + (size_t)i * 8);
    const f32x4 b = *(const f32x4*)(x + (size_t)i * 8 + 4);
    *(bf16x8*)(xb + (size_t)i * 8) = cvt8(a, b);
}

// ---------------- Kernel 1: gated = silu(x@w1^T) * (x@w3^T), bf16 out ----------
// Rebuilt in k2's image (k2 measured 7.1 TB/s): serial 2-barrier loop,
// reg-staged float4->cvt->ushort4 weight staging, SMALL LDS (18.4 KB =
// w1+w3 bf16 only) for max resident blocks/CU (TLP saturates the read path).
// A-fragments come per-lane from the pre-cast bf16 x (L2-resident) — no x
// staging at all. grid (NF/64, NE) jt-major, block 256 (4 waves).
__global__ __launch_bounds__(256, 2)
void k1_gate(const ushort* __restrict__ xb,
             const float* __restrict__ w1,
             const float* __restrict__ w3,
             ushort* __restrict__ g) {
    __shared__ ushort lW1[64 * PITCH];   // 9.2 KB
    __shared__ ushort lW3[64 * PITCH];   // 9.2 KB

    const int jt   = blockIdx.x;               // ff 64-tile (0..43)
    const int e    = blockIdx.y;               // expert
    const int tid  = threadIdx.x;
    const int lane = tid & 63;
    const int wid  = tid >> 6;
    const int m15  = lane & 15;
    const int hi   = lane >> 4;
    const int mrow = wid * 16 + m15;

    const ushort* xA = xb + (size_t)e * TPE * NH + (size_t)mrow * NH;
    const float*  B1 = w1 + ((size_t)e * NF + (size_t)jt * 64) * NH;
    const float*  B3 = w3 + ((size_t)e * NF + (size_t)jt * 64) * NH;

    f32x4 acc1[4], acc3[4];
    #pragma unroll
    for (int nf = 0; nf < 4; ++nf) {
        acc1[nf] = f32x4{0.f, 0.f, 0.f, 0.f};
        acc3[nf] = f32x4{0.f, 0.f, 0.f, 0.f};
    }

    const int srow = tid >> 4;         // staging row base (0..15)
    const int sc4  = (tid & 15) * 4;   // staging dword col

    for (int kt = 0; kt < NH / 64; ++kt) {     // 16 iters
        const size_t kb = (size_t)kt * 64;
        __syncthreads();                        // readers done with LDS
        // stage w1/w3 (64 rows x 64 k f32 each): 4 rounds of float4 -> ushort4
        #pragma unroll
        for (int r = 0; r < 4; ++r) {
            const int row = srow + r * 16;
            const size_t goff = (size_t)row * NH + kb + sc4;
            const float4 v1 = *(const float4*)(B1 + goff);
            const float4 v3 = *(const float4*)(B3 + goff);
            ushort4 u1, u3;
            u1.x = f2bf(v1.x); u1.y = f2bf(v1.y); u1.z = f2bf(v1.z); u1.w = f2bf(v1.w);
            u3.x = f2bf(v3.x); u3.y = f2bf(v3.y); u3.z = f2bf(v3.z); u3.w = f2bf(v3.w);
            *(ushort4*)(&lW1[row * PITCH + sc4]) = u1;
            *(ushort4*)(&lW3[row * PITCH + sc4]) = u3;
        }
        __syncthreads();                        // tile staged

        #pragma unroll
        for (int ks = 0; ks < 2; ++ks) {
            const int koff = ks * 32 + hi * 8;
            // A-fragment straight from global bf16 x (L2-hot, hoisted early)
            const bf16x8 af = *(const bf16x8*)(xA + kb + koff);
            #pragma unroll
            for (int nf = 0; nf < 4; ++nf) {
                const int bo = (nf * 16 + m15) * PITCH + koff;
                const bf16x8 b1 = *(const bf16x8*)(&lW1[bo]);
                acc1[nf] = __builtin_amdgcn_mfma_f32_16x16x32_bf16(af, b1, acc1[nf], 0, 0, 0);
                const bf16x8 b3 = *(const bf16x8*)(&lW3[bo]);
                acc3[nf] = __builtin_amdgcn_mfma_f32_16x16x32_bf16(af, b3, acc3[nf], 0, 0, 0);
            }
        }
    }

    // epilogue: SwiGLU, bf16 gated. C/D layout: col=lane&15, row=(lane>>4)*4+i
    #pragma unroll
    for (int nf = 0; nf < 4; ++nf) {
        #pragma unroll
        for (int i = 0; i < 4; ++i) {
            const float h1v = acc1[nf][i];
            const float h3v = acc3[nf][i];
            const float s   = (h1v / (1.f + __expf(-h1v))) * h3v;
            const int row = wid * 16 + (hi * 4) + i;
            const int col = jt * 64 + nf * 16 + m15;
            const size_t t = (size_t)e * TPE + row;
            g[t * NF + col] = f2bf(s);
        }
    }
}

// ---------------- Kernel 2: out = gated @ w2 (per expert), fp32 out ------------
// (unchanged — measured ~104 us at ~7.1 TB/s on w2; at roofline)
__global__ __launch_bounds__(256, 2)
void k2_down(const ushort* __restrict__ g,
             const float* __restrict__ w2,
             float* __restrict__ out) {
    __shared__ ushort lA[64 * PITCH];
    __shared__ ushort lB[64 * PITCH];

    const int jt   = blockIdx.x;
    const int e    = blockIdx.y;
    const int tid  = threadIdx.x;
    const int lane = tid & 63;
    const int wid  = tid >> 6;

    const ushort* A = g  + (size_t)e * TPE * NF;
    const float*  B = w2 + (size_t)e * NF * NH + (size_t)jt * 64;
    float* O = out + (size_t)e * TPE * NH + (size_t)jt * 64;

    f32x4 acc[4];
    for (int nf = 0; nf < 4; ++nf) acc[nf] = f32x4{0.f, 0.f, 0.f, 0.f};

    for (int kt = 0; kt < NF / 64; ++kt) {   // 44 iters
        __syncthreads();
        #pragma unroll
        for (int r = 0; r < 2; ++r) {
            const int q   = tid + r * 256;
            const int row = q >> 3;
            const int k8  = (q & 7) * 8;
            *(bf16x8*)(&lA[row * PITCH + k8]) =
                *(const bf16x8*)(A + (size_t)row * NF + kt * 64 + k8);
        }
        {
            const int n  = tid & 63;
            const int kq = (tid >> 6) * 4;
            #pragma unroll
            for (int r = 0; r < 4; ++r) {
                const int ks = kq + r * 16;
                const size_t base = (size_t)(kt * 64 + ks) * NH + n;
                const float f0 = B[base];
                const float f1 = B[base + NH];
                const float f2 = B[base + 2 * (size_t)NH];
                const float f3 = B[base + 3 * (size_t)NH];
                ushort4 b;
                b.x = f2bf(f0); b.y = f2bf(f1); b.z = f2bf(f2); b.w = f2bf(f3);
                *(ushort4*)(&lB[n * PITCH + ks]) = b;
            }
        }
        __syncthreads();

        const int mrow = wid * 16 + (lane & 15);
        #pragma unroll
        for (int ks = 0; ks < 2; ++ks) {
            const int koff = ks * 32 + ((lane >> 4) * 8);
            const bf16x8 af = *(const bf16x8*)(&lA[mrow * PITCH + koff]);
            #pragma unroll
            for (int nf = 0; nf < 4; ++nf) {
                const bf16x8 bfr = *(const bf16x8*)(&lB[(nf * 16 + (lane & 15)) * PITCH + koff]);
                acc[nf] = __builtin_amdgcn_mfma_f32_16x16x32_bf16(af, bfr, acc[nf], 0, 0, 0);
            }
        }
    }

    #pragma unroll
    for (int nf = 0; nf < 4; ++nf) {
        #pragma unroll
        for (int i = 0; i < 4; ++i) {
            const int row = wid * 16 + ((lane >> 4) * 4) + i;
            const int col = nf * 16 + (lane & 15);
            O[(size_t)row * NH + col] = acc[nf][i];
        }
    }
}

extern "C" void kernel_launch(void* const* d_in, const int* in_sizes, int n_in,
                              void* d_out, int out_size, void* d_ws, size_t ws_size,
                              hipStream_t stream) {
    const float* x  = (const float*)d_in[0];
    const float* w1 = (const float*)d_in[2];
    const float* w3 = (const float*)d_in[3];
    const float* w2 = (const float*)d_in[4];
    float* out = (float*)d_out;
    ushort* gated = (ushort*)d_ws;                         // 23.1 MB
    ushort* xbf   = (ushort*)((char*)d_ws + (32u << 20));  // 8.4 MB @ +32MB

    xcast<<<dim3((TPE * NE * NH) / (256 * 8)), dim3(256), 0, stream>>>(x, xbf);

    dim3 g1(NF / 64, NE);    // (44, 64) jt-major
    k1_gate<<<g1, dim3(256), 0, stream>>>(xbf, w1, w3, gated);

    dim3 g2(NH / 64, NE);    // (16, 64)
    k2_down<<<g2, dim3(256), 0, stream>>>(gated, w2, out);
}